// Round 11
// baseline (106.903 us; speedup 1.0000x reference)
//
#include <hip/hip_runtime.h>
#include <cstdint>

namespace {

constexpr int BB = 64;
constexpr int DDIM = 196608;          // 3*256*256
constexpr float T_SCALE = 0.99f;      // 1 - 1/MAX_TIMESTEPS

// ws layout (floats). Per-block partials in bigp mirror ws offsets for idx<NRED.
constexpr int WS_ZD   = 0;            // 64*64  ZD[i][j] = z_i . d_j
constexpr int WS_DD   = 4096;         // 64*64  DD[i][j] = d_i . d_j
constexpr int WS_Z2   = 8192;         // 64     |z_i|^2
constexpr int WS_ELEM = 8256;         // 1      elementwise loss total
constexpr int NRED    = 8257;
constexpr int WS_BIGP = 8384;
constexpr int PSTRIDE = 8272;         // per-block stride (16B aligned)
constexpr int NB_MAIN = 512;          // 2 blocks/CU exactly, zero tail

using f32x4  = __attribute__((ext_vector_type(4))) float;
using bf16x8 = __attribute__((ext_vector_type(8))) __bf16;

__device__ inline f32x4 MFMA(bf16x8 a, bf16x8 b, f32x4 c) {
  return __builtin_amdgcn_mfma_f32_16x16x32_bf16(a, b, c, 0, 0, 0);
}

// T4 barrier: LDS visibility only -- NO vmcnt drain (unlike __syncthreads,
// which emits s_waitcnt vmcnt(0) lgkmcnt(0) and kills cross-phase prefetch).
// The compiler's dep tracking emits counted vmcnt(N) at register-use sites.
__device__ inline void barrier_lgkm() {
  asm volatile("s_waitcnt lgkmcnt(0)" ::: "memory");
  __builtin_amdgcn_s_barrier();
}

__global__ void k_init(float* __restrict__ ws) {
  int idx = blockIdx.x * 256 + threadIdx.x;
  if (idx < NRED) ws[idx] = 0.0f;
}

// ---------------------------------------------------------------------------
// k_main: dual Grams (bf16 3-split) + z2 + elem loss. 512 thr / 8 waves.
//   ZD = zh(dh+dm+dl)+zm(dh+dm)+zl*dh ; DD same with d both sides.
// Subtile = 32 k, SUBT=12 (grid 512 = 2 blocks/CU, K-chunk 384).
// dbuf LDS, ONE raw barrier per subtile (lgkm drain only -- T4): loads for
// subtile s+2 stay IN FLIGHT across the phase-s barrier; their vmcnt wait
// lands in STAGE(s+1), which runs AFTER MMA(s), so HBM/L3 latency hides
// under the MFMA + ds_read stream. R7-R9 all plateaued at ~80us profiled
// because __syncthreads' vmcnt(0) drained the pipeline 12-24x per block.
// Phase s: LOADTO(s+2, free set) -> MMA(s) -> STAGE(s+1, other set) -> bar.
// LDS layout per buf: 3 spaces x [64 rows][128B], chunks XOR-swizzled
//   ch = (((tile&1)<<2)+(c4>>1)) ^ (r&7)  (R8/R9-verified, absmax 0).
// ---------------------------------------------------------------------------
template <int SUBT, bool ATOMIC>
__global__ __launch_bounds__(512) void k_main(
    const float* __restrict__ data, const float* __restrict__ noise,
    const float* __restrict__ pmean, const float* __restrict__ plogv,
    float* __restrict__ ws, float* __restrict__ bigp) {
  __shared__ __align__(16) char lds[49152];   // 2 bufs x 3 spaces x 8 KB
  __shared__ float esm[8];

  const int t  = threadIdx.x;
  const int wv = t >> 6;
  const int l  = t & 63;
  const int g  = wv >> 2;              // 0: ZD, 1: DD
  const int m0 = (wv & 3) << 4;        // output row-band
  const int r  = t >> 3;               // staging row 0..63
  const int c4 = t & 7;                // staging 4-float chunk
  const size_t sbase =
      (size_t)r * DDIM + (size_t)blockIdx.x * (SUBT * 32) + (c4 << 2);
  float* dst = ATOMIC ? ws : (bigp + (size_t)blockIdx.x * PSTRIDE);

  f32x4 acc[4];
#pragma unroll
  for (int b = 0; b < 4; ++b) acc[b] = 0.0f;
  float z2acc = 0.0f, eacc = 0.0f;

  float4 dA, zA, pA, gA, dB, zB, pB, gB;   // double staging sets

  auto LOADTO = [&](int s, float4& d_, float4& z_, float4& p_, float4& g_) {
    const size_t off = sbase + (s << 5);
    d_ = *(const float4*)(data  + off);
    z_ = *(const float4*)(noise + off);
    p_ = *(const float4*)(pmean + off);
    g_ = *(const float4*)(plogv + off);
  };

  // split 4 floats into tiles tbase..tbase+2 of buffer buf (write immediately)
  auto SPLITW = [&](int buf, const float4& v, int tbase) {
    const float* f = (const float*)&v;
    uint32_t h[2], m[2], lo[2];
#pragma unroll
    for (int p = 0; p < 2; ++p) {
      const float a = f[2 * p], b = f[2 * p + 1];
      const uint32_t ha = __float_as_uint(a) & 0xFFFF0000u;
      const uint32_t hb = __float_as_uint(b) & 0xFFFF0000u;
      h[p] = (ha >> 16) | hb;
      const float ra = a - __uint_as_float(ha);
      const float rb = b - __uint_as_float(hb);
      const uint32_t ma = __float_as_uint(ra) & 0xFFFF0000u;
      const uint32_t mb = __float_as_uint(rb) & 0xFFFF0000u;
      m[p] = (ma >> 16) | mb;
      const float sa = ra - __uint_as_float(ma);
      const float sb = rb - __uint_as_float(mb);
      lo[p] = (__float_as_uint(sa) >> 16) | (__float_as_uint(sb) & 0xFFFF0000u);
    }
#pragma unroll
    for (int sp = 0; sp < 3; ++sp) {
      const int tile = tbase + sp;
      const int byte = buf + ((tile >> 1) << 13) + (r << 7) +
                       (((((tile & 1) << 2) + (c4 >> 1)) ^ (r & 7)) << 4) +
                       ((c4 & 1) << 3);
      const uint32_t* pk = (sp == 0) ? h : (sp == 1) ? m : lo;
      *(uint2*)(lds + byte) = uint2{pk[0], pk[1]};
    }
  };

  auto STAGE = [&](int s, const float4& d_, const float4& z_, const float4& p_,
                   const float4& g_) {
    const int buf = (s & 1) * 24576;
    SPLITW(buf, z_, 0);
    SPLITW(buf, d_, 3);
    const float* df = (const float*)&d_;
    const float* zf = (const float*)&z_;
    const float* pf = (const float*)&p_;
    const float* gf = (const float*)&g_;
#pragma unroll
    for (int p = 0; p < 4; ++p) {
      const float d = df[p], z = zf[p], pm = pf[p], pl = gf[p];
      eacc += 0.5f * (pm * pm + __expf(pl) * pl) - pm * (d - z);
      z2acc += z * z;
    }
  };

  auto FRAG = [&](int buf, int tile, int row) -> bf16x8 {
    const int byte = buf + ((tile >> 1) << 13) + (row << 7) +
                     (((((tile & 1) << 2) + (l >> 4)) ^ (row & 7)) << 4);
    return *(const bf16x8*)(lds + byte);
  };

  auto MMA = [&](int s) {
    const int buf = (s & 1) * 24576;
    const int ar  = m0 + (l & 15);
    bf16x8 af[3];
#pragma unroll
    for (int sp = 0; sp < 3; ++sp) af[sp] = FRAG(buf, g * 3 + sp, ar);
#pragma unroll
    for (int b = 0; b < 4; ++b) {
      const int br = (b << 4) + (l & 15);
      bf16x8 bd[3];
#pragma unroll
      for (int sp = 0; sp < 3; ++sp) bd[sp] = FRAG(buf, 3 + sp, br);
      acc[b] = MFMA(af[0], bd[0], acc[b]);
      acc[b] = MFMA(af[0], bd[1], acc[b]);
      acc[b] = MFMA(af[1], bd[0], acc[b]);
      acc[b] = MFMA(af[1], bd[1], acc[b]);
      acc[b] = MFMA(af[0], bd[2], acc[b]);
      acc[b] = MFMA(af[2], bd[0], acc[b]);
    }
  };

  // prologue: subtile 0 staged (set A), subtile 1 loaded (set B)
  LOADTO(0, dA, zA, pA, gA);
  STAGE(0, dA, zA, pA, gA);            // -> buf0
  LOADTO(1, dB, zB, pB, gB);
  barrier_lgkm();                      // buf0 visible; B loads stay in flight

  static_assert(SUBT % 2 == 0, "unroll-by-2 pipeline");
#pragma unroll
  for (int s = 0; s < SUBT; s += 2) {
    // even phase: compute s, stage s+1 (set B), issue loads for s+2 (set A)
    if (s + 2 < SUBT) LOADTO(s + 2, dA, zA, pA, gA);
    MMA(s);                                           // buf[s&1]
    if (s + 1 < SUBT) STAGE(s + 1, dB, zB, pB, gB);   // vmcnt wait hidden
    barrier_lgkm();
    if (s + 1 < SUBT) {
      // odd phase: compute s+1, stage s+2 (set A), loads for s+3 (set B)
      if (s + 3 < SUBT) LOADTO(s + 3, dB, zB, pB, gB);
      MMA(s + 1);
      if (s + 2 < SUBT) STAGE(s + 2, dA, zA, pA, gA);
      barrier_lgkm();
    }
  }

  // ---- z2 (8 staging lanes per row) / elem reductions ----
  {
    float v = z2acc;
    v += __shfl_xor(v, 1);
    v += __shfl_xor(v, 2);
    v += __shfl_xor(v, 4);
    if ((l & 7) == 0) {
      if (ATOMIC) atomicAdd(ws + WS_Z2 + r, v);
      else        dst[WS_Z2 + r] = v;
    }
  }
  {
    float ev = eacc;
#pragma unroll
    for (int m = 1; m <= 32; m <<= 1) ev += __shfl_xor(ev, m);
    if (l == 0) esm[wv] = ev;
  }
  __syncthreads();
  if (t == 0) {
    float s0 = 0.f;
#pragma unroll
    for (int e = 0; e < 8; ++e) s0 += esm[e];
    if (ATOMIC) atomicAdd(ws + WS_ELEM, s0);
    else        dst[WS_ELEM] = s0;
  }

  // ---- gram stores: C/D layout col=lane&15, row=4*(lane>>4)+reg ----
  const int grOff = (g == 0) ? WS_ZD : WS_DD;
#pragma unroll
  for (int b = 0; b < 4; ++b)
#pragma unroll
    for (int rg = 0; rg < 4; ++rg) {
      const int row = m0 + ((l >> 4) << 2) + rg;
      const int col = (b << 4) + (l & 15);
      if (ATOMIC) atomicAdd(ws + grOff + row * 64 + col, acc[b][rg]);
      else        dst[grOff + row * 64 + col] = acc[b][rg];
    }
}

// Atomic-free fold of nb per-block partials into ws[0..NRED):
// 4 waves each sum nb/4 blocks for their 64-float slice, LDS-fold, store.
__global__ __launch_bounds__(256) void k_reduce(const float* __restrict__ bigp,
                                                float* __restrict__ ws, int nb) {
  __shared__ float red[4][64];
  const int t = threadIdx.x;
  const int wv = t >> 6, l = t & 63;
  const int idx = blockIdx.x * 64 + l;
  const int per = nb >> 2;
  float s = 0.f;
  if (idx < NRED) {
    const float* p = bigp + (size_t)wv * per * PSTRIDE + idx;
#pragma unroll 4
    for (int b = 0; b < per; ++b) s += p[(size_t)b * PSTRIDE];
  }
  red[wv][l] = s;
  __syncthreads();
  if (wv == 0 && idx < NRED)
    ws[idx] = red[0][l] + red[1][l] + red[2][l] + red[3][l];
}

// ---------------------------------------------------------------------------
// k_smallfinal: softmax + Gram-space u^2 + final scalar (R8/R9-verified).
// ---------------------------------------------------------------------------
__global__ __launch_bounds__(1024) void k_smallfinal(
    const float* __restrict__ times, const float* __restrict__ ws,
    float* __restrict__ out) {
  __shared__ double u2s[64];
  const int t = threadIdx.x;
  const int wv = t >> 6;
  const int j = t & 63;

#pragma unroll
  for (int ii = 0; ii < 4; ++ii) {
    const int i = (wv << 2) + ii;
    const double tt = (double)(times[i] * T_SCALE);
    const double omt = 1.0 - tt;
    const double var = omt * omt + 1e-8;
    const double inv2v = 1.0 / (2.0 * var);
    const double zd = (double)ws[WS_ZD + (i << 6) + j];
    const double dd = (double)ws[WS_DD + (i << 6) + j];
    const double cross = omt * zd + tt * dd;
    const double d2j = (double)ws[WS_DD + j * 65];
    const double lg = (2.0 * tt * cross - tt * tt * d2j) * inv2v;
    double m = lg;
#pragma unroll
    for (int msk = 1; msk <= 32; msk <<= 1) m = fmax(m, __shfl_xor(m, msk));
    const double e = exp(lg - m);
    double S = e;
#pragma unroll
    for (int msk = 1; msk <= 32; msk <<= 1) S += __shfl_xor(S, msk);
    const double wgt = e / S;

    double inner = 0.0;
#pragma unroll 8
    for (int j2 = 0; j2 < 64; ++j2)
      inner += __shfl(wgt, j2) * (double)ws[WS_DD + (j << 6) + j2];
    double s1 = wgt * inner;
    double s2 = wgt * cross;
#pragma unroll
    for (int msk = 1; msk <= 32; msk <<= 1) {
      s1 += __shfl_xor(s1, msk);
      s2 += __shfl_xor(s2, msk);
    }
    if (j == 0) {
      const double zdii = (double)ws[WS_ZD + i * 65];
      const double d2i  = (double)ws[WS_DD + i * 65];
      const double z2i  = (double)ws[WS_Z2 + i];
      const double n2 = omt * omt * z2i + 2.0 * tt * omt * zdii + tt * tt * d2i;
      const double den = omt + 1e-8;
      u2s[i] = (s1 - 2.0 * s2 + n2) / (den * den);
    }
  }
  __syncthreads();
  if (wv == 0) {
    double v = 0.5 * u2s[j];
    if (j == 0) v += (double)ws[WS_ELEM];
#pragma unroll
    for (int m = 1; m <= 32; m <<= 1) v += __shfl_xor(v, m);
    if (j == 0) out[0] = (float)(v / (double)((size_t)BB * DDIM));
  }
}

}  // namespace

extern "C" void kernel_launch(void* const* d_in, const int* in_sizes, int n_in,
                              void* d_out, int out_size, void* d_ws, size_t ws_size,
                              hipStream_t stream) {
  const float* data  = (const float*)d_in[0];
  const float* noise = (const float*)d_in[1];
  const float* times = (const float*)d_in[2];
  const float* pmean = (const float*)d_in[3];
  const float* plogv = (const float*)d_in[4];
  float* out = (float*)d_out;
  float* ws  = (float*)d_ws;
  float* bigp = ws + WS_BIGP;

  const bool fits =
      ws_size >= ((size_t)WS_BIGP + (size_t)NB_MAIN * PSTRIDE) * sizeof(float);

  if (fits) {
    k_main<12, false><<<dim3(NB_MAIN), dim3(512), 0, stream>>>(
        data, noise, pmean, plogv, ws, bigp);
    k_reduce<<<dim3(130), dim3(256), 0, stream>>>(bigp, ws, NB_MAIN);
  } else {
    k_init<<<dim3(33), dim3(256), 0, stream>>>(ws);
    k_main<12, true><<<dim3(NB_MAIN), dim3(512), 0, stream>>>(
        data, noise, pmean, plogv, ws, bigp);
  }
  k_smallfinal<<<dim3(1), dim3(1024), 0, stream>>>(times, ws, out);
}

// Round 12
// 93.705 us; speedup vs baseline: 1.1409x; 1.1409x over previous
//
#include <hip/hip_runtime.h>
#include <cstdint>

namespace {

constexpr int BB = 64;
constexpr int DDIM = 196608;          // 3*256*256
constexpr float T_SCALE = 0.99f;      // 1 - 1/MAX_TIMESTEPS

// ws layout (floats). Per-block partials in bigp mirror ws offsets for idx<NRED.
constexpr int WS_ZD   = 0;            // 64*64  ZD[i][j] = z_i . d_j
constexpr int WS_DD   = 4096;         // 64*64  DD[i][j] = d_i . d_j
constexpr int WS_Z2   = 8192;         // 64     |z_i|^2
constexpr int WS_ELEM = 8256;         // 1      elementwise loss total
constexpr int NRED    = 8257;
constexpr int WS_BIGP = 8384;
constexpr int PSTRIDE = 8272;         // per-block stride (16B aligned)
constexpr int NB_MAIN = 768;          // 3 blocks/CU x 256 CU, zero tail

using f32x4  = __attribute__((ext_vector_type(4))) float;
using bf16x8 = __attribute__((ext_vector_type(8))) __bf16;

__device__ inline f32x4 MFMA(bf16x8 a, bf16x8 b, f32x4 c) {
  return __builtin_amdgcn_mfma_f32_16x16x32_bf16(a, b, c, 0, 0, 0);
}

__global__ void k_init(float* __restrict__ ws) {
  int idx = blockIdx.x * 256 + threadIdx.x;
  if (idx < NRED) ws[idx] = 0.0f;
}

// ---------------------------------------------------------------------------
// k_main: EXACT R7 structure (best wall 57.9us, VGPR 64) at 3 blocks/CU.
// Dual Grams via exact bf16 3-split + z2 + elem loss. 512 thr / 8 waves.
//   ZD = zh(dh+dm+dl)+zm(dh+dm)+zl*dh ; DD same with d both sides.
// Subtile = 64 k, SUBT=4 (grid 768 -> k-chunk 256; R7 point VGPR=64 +
// LDS 48.5KB fits 3 blocks/CU -> 24 waves/CU resident; R9's 768 failed
// because VGPR=100 allowed only 2/CU -> half-machine tail).
// Pipeline per subtile: {SPLITCALC(s+1) || MMA(s)} sync {DSW(s+1),
// LOAD(s+2)} sync.  VALU split work co-issues with the MFMA stream;
// occupancy (6 waves/SIMD) hides the barrier drains -- the R7-R10 lesson:
// TLP beats per-wave pipeline depth on this allocator.
// LDS: 6 spaces x [64 rows][128B], 16B chunks XOR-swizzled ch = c ^ (r&7)
// (verified 0 read conflicts, absmax 0.0 across R6-R10).
// ---------------------------------------------------------------------------
template <int SUBT, bool ATOMIC>
__global__ __launch_bounds__(512) void k_main(
    const float* __restrict__ data, const float* __restrict__ noise,
    const float* __restrict__ pmean, const float* __restrict__ plogv,
    float* __restrict__ ws, float* __restrict__ bigp) {
  __shared__ __align__(16) short lds[6 * 4096];   // zh zm zl dh dm dl
  __shared__ float esm[8];

  const int t  = threadIdx.x;
  const int wv = t >> 6;
  const int l  = t & 63;
  const int g  = wv >> 2;              // 0: ZD, 1: DD
  const int m0 = (wv & 3) << 4;        // output row-band
  const int sr = t >> 3;               // staging row 0..63
  const int c0 = t & 7;                // staging chunk (8 floats)
  const int chunk0 = blockIdx.x * (SUBT << 6);
  float* dst = ATOMIC ? ws : (bigp + (size_t)blockIdx.x * PSTRIDE);

  f32x4 acc[4];
#pragma unroll
  for (int b = 0; b < 4; ++b) acc[b] = 0.0f;
  float z2acc = 0.0f, eacc = 0.0f;
  float4 dv[2], zv[2], pv[2], gv[2];   // in-flight staging regs
  uint4 sZ[3], sD[3];                  // split results awaiting ds_write

  auto LOAD = [&](int s) {
    const size_t base = (size_t)sr * DDIM + chunk0 + (s << 6) + (c0 << 3);
#pragma unroll
    for (int i = 0; i < 2; ++i) {
      dv[i] = *(const float4*)(data  + base + (i << 2));
      zv[i] = *(const float4*)(noise + base + (i << 2));
      pv[i] = *(const float4*)(pmean + base + (i << 2));
      gv[i] = *(const float4*)(plogv + base + (i << 2));
    }
  };

  auto SPLIT8 = [&](const float4* v, uint4& H, uint4& M, uint4& L) {
    uint32_t h[4], m[4], lo[4];
    const float* f = (const float*)v;
#pragma unroll
    for (int p = 0; p < 4; ++p) {
      const float a = f[2 * p], b = f[2 * p + 1];
      const uint32_t ha = __float_as_uint(a) & 0xFFFF0000u;
      const uint32_t hb = __float_as_uint(b) & 0xFFFF0000u;
      h[p] = (ha >> 16) | hb;
      const float ra = a - __uint_as_float(ha);
      const float rb = b - __uint_as_float(hb);
      const uint32_t ma = __float_as_uint(ra) & 0xFFFF0000u;
      const uint32_t mb = __float_as_uint(rb) & 0xFFFF0000u;
      m[p] = (ma >> 16) | mb;
      const float sa = ra - __uint_as_float(ma);
      const float sb = rb - __uint_as_float(mb);
      lo[p] = (__float_as_uint(sa) >> 16) | (__float_as_uint(sb) & 0xFFFF0000u);
    }
    H = uint4{h[0], h[1], h[2], h[3]};
    M = uint4{m[0], m[1], m[2], m[3]};
    L = uint4{lo[0], lo[1], lo[2], lo[3]};
  };

  // split + elem + z2 on the regs from the last LOAD (register-only; the
  // compiler interleaves this VALU work with the MFMA stream below)
  auto SPLITCALC = [&]() {
    const float* df = (const float*)dv;
    const float* zf = (const float*)zv;
    const float* pf = (const float*)pv;
    const float* gf = (const float*)gv;
#pragma unroll
    for (int p = 0; p < 8; ++p) {
      const float d = df[p], z = zf[p], pm = pf[p], pl = gf[p];
      const float fc = d - z;
      eacc += 0.5f * (pm * pm + __expf(pl) * pl) - pm * fc;
      z2acc += z * z;
    }
    SPLIT8(zv, sZ[0], sZ[1], sZ[2]);
    SPLIT8(dv, sD[0], sD[1], sD[2]);
  };

  auto DSW = [&]() {
    char* base = (char*)lds + sr * 128 + ((c0 ^ (sr & 7)) << 4);
#pragma unroll
    for (int sp = 0; sp < 3; ++sp) {
      *(uint4*)(base + sp * 8192)       = sZ[sp];
      *(uint4*)(base + (3 + sp) * 8192) = sD[sp];
    }
  };

  auto MMA = [&]() {
#pragma unroll
    for (int s2 = 0; s2 < 2; ++s2) {
      const int rA   = m0 + (l & 15);
      const int cA   = (s2 << 2) + (l >> 4);
      const int offA = rA * 128 + ((cA ^ (rA & 7)) << 4);
      bf16x8 af[3];
#pragma unroll
      for (int sp = 0; sp < 3; ++sp)
        af[sp] = *(const bf16x8*)((const char*)lds + (g * 3 + sp) * 8192 + offA);
#pragma unroll
      for (int b = 0; b < 4; ++b) {
        const int rB   = (b << 4) + (l & 15);
        const int offB = rB * 128 + ((cA ^ (rB & 7)) << 4);
        bf16x8 bd[3];
#pragma unroll
        for (int sp = 0; sp < 3; ++sp)
          bd[sp] = *(const bf16x8*)((const char*)lds + (3 + sp) * 8192 + offB);
        acc[b] = MFMA(af[0], bd[0], acc[b]);
        acc[b] = MFMA(af[0], bd[1], acc[b]);
        acc[b] = MFMA(af[1], bd[0], acc[b]);
        acc[b] = MFMA(af[1], bd[1], acc[b]);
        acc[b] = MFMA(af[0], bd[2], acc[b]);
        acc[b] = MFMA(af[2], bd[0], acc[b]);
      }
    }
  };

  // prologue: stage tile 0, issue loads for tile 1
  LOAD(0);
  SPLITCALC();
  DSW();
  LOAD(1);
  __syncthreads();                     // tile 0 visible

  for (int s = 0; s < SUBT; ++s) {
    if (s + 1 < SUBT) SPLITCALC();     // VALU stream (tile s+1)
    MMA();                             // MFMA stream (tile s) — co-issued
    __syncthreads();                   // tile s reads done
    if (s + 1 < SUBT) {
      DSW();                           // commit tile s+1
      if (s + 2 < SUBT) LOAD(s + 2);   // issue next loads
      __syncthreads();                 // tile s+1 visible
    }
  }

  // ---- z2 (8 staging lanes per row) / elem reductions ----
  {
    float v = z2acc;
    v += __shfl_xor(v, 1);
    v += __shfl_xor(v, 2);
    v += __shfl_xor(v, 4);
    if ((l & 7) == 0) {
      if (ATOMIC) atomicAdd(ws + WS_Z2 + sr, v);
      else        dst[WS_Z2 + sr] = v;
    }
  }
  {
    float ev = eacc;
#pragma unroll
    for (int m = 1; m <= 32; m <<= 1) ev += __shfl_xor(ev, m);
    if (l == 0) esm[wv] = ev;
  }
  __syncthreads();
  if (t == 0) {
    float s0 = 0.f;
#pragma unroll
    for (int e = 0; e < 8; ++e) s0 += esm[e];
    if (ATOMIC) atomicAdd(ws + WS_ELEM, s0);
    else        dst[WS_ELEM] = s0;
  }

  // ---- gram stores: C/D layout col=lane&15, row=4*(lane>>4)+reg ----
  const int grOff = (g == 0) ? WS_ZD : WS_DD;
#pragma unroll
  for (int b = 0; b < 4; ++b)
#pragma unroll
    for (int rg = 0; rg < 4; ++rg) {
      const int row = m0 + ((l >> 4) << 2) + rg;
      const int col = (b << 4) + (l & 15);
      if (ATOMIC) atomicAdd(ws + grOff + row * 64 + col, acc[b][rg]);
      else        dst[grOff + row * 64 + col] = acc[b][rg];
    }
}

// Atomic-free fold of nb per-block partials into ws[0..NRED):
// 4 waves each sum nb/4 blocks for their 64-float slice, LDS-fold, store.
__global__ __launch_bounds__(256) void k_reduce(const float* __restrict__ bigp,
                                                float* __restrict__ ws, int nb) {
  __shared__ float red[4][64];
  const int t = threadIdx.x;
  const int wv = t >> 6, l = t & 63;
  const int idx = blockIdx.x * 64 + l;
  const int per = nb >> 2;
  float s = 0.f;
  if (idx < NRED) {
    const float* p = bigp + (size_t)wv * per * PSTRIDE + idx;
#pragma unroll 4
    for (int b = 0; b < per; ++b) s += p[(size_t)b * PSTRIDE];
  }
  red[wv][l] = s;
  __syncthreads();
  if (wv == 0 && idx < NRED)
    ws[idx] = red[0][l] + red[1][l] + red[2][l] + red[3][l];
}

// ---------------------------------------------------------------------------
// k_smallfinal: softmax + Gram-space u^2 + final scalar (R8-R10 verified).
// ---------------------------------------------------------------------------
__global__ __launch_bounds__(1024) void k_smallfinal(
    const float* __restrict__ times, const float* __restrict__ ws,
    float* __restrict__ out) {
  __shared__ double u2s[64];
  const int t = threadIdx.x;
  const int wv = t >> 6;
  const int j = t & 63;

#pragma unroll
  for (int ii = 0; ii < 4; ++ii) {
    const int i = (wv << 2) + ii;
    const double tt = (double)(times[i] * T_SCALE);
    const double omt = 1.0 - tt;
    const double var = omt * omt + 1e-8;
    const double inv2v = 1.0 / (2.0 * var);
    const double zd = (double)ws[WS_ZD + (i << 6) + j];
    const double dd = (double)ws[WS_DD + (i << 6) + j];
    const double cross = omt * zd + tt * dd;
    const double d2j = (double)ws[WS_DD + j * 65];
    const double lg = (2.0 * tt * cross - tt * tt * d2j) * inv2v;
    double m = lg;
#pragma unroll
    for (int msk = 1; msk <= 32; msk <<= 1) m = fmax(m, __shfl_xor(m, msk));
    const double e = exp(lg - m);
    double S = e;
#pragma unroll
    for (int msk = 1; msk <= 32; msk <<= 1) S += __shfl_xor(S, msk);
    const double wgt = e / S;

    double inner = 0.0;
#pragma unroll 8
    for (int j2 = 0; j2 < 64; ++j2)
      inner += __shfl(wgt, j2) * (double)ws[WS_DD + (j << 6) + j2];
    double s1 = wgt * inner;
    double s2 = wgt * cross;
#pragma unroll
    for (int msk = 1; msk <= 32; msk <<= 1) {
      s1 += __shfl_xor(s1, msk);
      s2 += __shfl_xor(s2, msk);
    }
    if (j == 0) {
      const double zdii = (double)ws[WS_ZD + i * 65];
      const double d2i  = (double)ws[WS_DD + i * 65];
      const double z2i  = (double)ws[WS_Z2 + i];
      const double n2 = omt * omt * z2i + 2.0 * tt * omt * zdii + tt * tt * d2i;
      const double den = omt + 1e-8;
      u2s[i] = (s1 - 2.0 * s2 + n2) / (den * den);
    }
  }
  __syncthreads();
  if (wv == 0) {
    double v = 0.5 * u2s[j];
    if (j == 0) v += (double)ws[WS_ELEM];
#pragma unroll
    for (int m = 1; m <= 32; m <<= 1) v += __shfl_xor(v, m);
    if (j == 0) out[0] = (float)(v / (double)((size_t)BB * DDIM));
  }
}

}  // namespace

extern "C" void kernel_launch(void* const* d_in, const int* in_sizes, int n_in,
                              void* d_out, int out_size, void* d_ws, size_t ws_size,
                              hipStream_t stream) {
  const float* data  = (const float*)d_in[0];
  const float* noise = (const float*)d_in[1];
  const float* times = (const float*)d_in[2];
  const float* pmean = (const float*)d_in[3];
  const float* plogv = (const float*)d_in[4];
  float* out = (float*)d_out;
  float* ws  = (float*)d_ws;
  float* bigp = ws + WS_BIGP;

  const bool fits =
      ws_size >= ((size_t)WS_BIGP + (size_t)NB_MAIN * PSTRIDE) * sizeof(float);

  if (fits) {
    k_main<4, false><<<dim3(NB_MAIN), dim3(512), 0, stream>>>(
        data, noise, pmean, plogv, ws, bigp);
    k_reduce<<<dim3(130), dim3(256), 0, stream>>>(bigp, ws, NB_MAIN);
  } else {
    k_init<<<dim3(33), dim3(256), 0, stream>>>(ws);
    k_main<4, true><<<dim3(NB_MAIN), dim3(512), 0, stream>>>(
        data, noise, pmean, plogv, ws, bigp);
  }
  k_smallfinal<<<dim3(1), dim3(1024), 0, stream>>>(times, ws, out);
}

// Round 13
// 58.836 us; speedup vs baseline: 1.8170x; 1.5927x over previous
//
#include <hip/hip_runtime.h>
#include <cstdint>

namespace {

constexpr int BB = 64;
constexpr int DDIM = 196608;          // 3*256*256
constexpr float T_SCALE = 0.99f;      // 1 - 1/MAX_TIMESTEPS

// ws layout (floats). Per-block partials in bigp mirror ws offsets for idx<NRED.
constexpr int WS_ZD   = 0;            // 64*64  ZD[i][j] = z_i . d_j
constexpr int WS_DD   = 4096;         // 64*64  DD[i][j] = d_i . d_j
constexpr int WS_Z2   = 8192;         // 64     |z_i|^2
constexpr int WS_ELEM = 8256;         // 1      elementwise loss total
constexpr int NRED    = 8257;
constexpr int WS_U2   = 8320;         // 64 per-row sum(u^2)
constexpr int WS_BIGP = 8384;
constexpr int PSTRIDE = 8272;         // per-block stride (16B aligned)

using f32x4  = __attribute__((ext_vector_type(4))) float;
using bf16x8 = __attribute__((ext_vector_type(8))) __bf16;

__device__ inline f32x4 MFMA(bf16x8 a, bf16x8 b, f32x4 c) {
  return __builtin_amdgcn_mfma_f32_16x16x32_bf16(a, b, c, 0, 0, 0);
}

__global__ void k_init(float* __restrict__ ws) {
  int idx = blockIdx.x * 256 + threadIdx.x;
  if (idx < NRED) ws[idx] = 0.0f;
}

// ---------------------------------------------------------------------------
// k_main (EXACT R7 restore -- best measured wall 57.9us):
// dual Grams via exact bf16 3-split, z2, elem loss. 512 thr / 8 waves.
//   ZD = zh(dh+dm+dl)+zm(dh+dm)+zl*dh ; DD same with d-splits both sides.
// Grid 512, SUBT=6 (k-chunk 384). Per subtile: {SPLITCALC(s+1) || MMA(s)}
// sync {DSW(s+1), LOAD(s+2)} sync. pm/plv prefetched one phase ahead.
// LDS: 6 spaces x [64 rows][128B], 16B chunks XOR-swizzled ch = c ^ (r&7).
// R8-R11 lesson: every structural departure from this point (single-barrier
// dbuf, double reg-sets, raw T4 barriers, SUBT/grid/tail changes) regressed
// wall to 84-107us; the deltas lived in occupancy dynamics + tail kernels,
// not in the profiled k_main body. This config is the measured optimum.
// ---------------------------------------------------------------------------
template <int SUBT, bool ATOMIC>
__global__ __launch_bounds__(512) void k_main(
    const float* __restrict__ data, const float* __restrict__ noise,
    const float* __restrict__ pmean, const float* __restrict__ plogv,
    float* __restrict__ ws, float* __restrict__ bigp) {
  __shared__ __align__(16) short lds[6 * 4096];   // zh zm zl dh dm dl
  __shared__ float esm[8];

  const int t  = threadIdx.x;
  const int wv = t >> 6;
  const int l  = t & 63;
  const int g  = wv >> 2;              // 0: ZD, 1: DD
  const int m0 = (wv & 3) << 4;        // output row-band
  const int sr = t >> 3;               // staging row 0..63
  const int c0 = t & 7;                // staging chunk (8 floats)
  const int chunk0 = blockIdx.x * (SUBT << 6);
  float* dst = ATOMIC ? ws : (bigp + (size_t)blockIdx.x * PSTRIDE);

  f32x4 acc[4];
#pragma unroll
  for (int b = 0; b < 4; ++b) acc[b] = 0.0f;
  float z2acc = 0.0f, eacc = 0.0f;
  float4 dv[2], zv[2], pv[2], gv[2];   // in-flight staging regs
  uint4 sZ[3], sD[3];                  // split results awaiting ds_write

  auto LOAD = [&](int s) {
    const size_t base = (size_t)sr * DDIM + chunk0 + (s << 6) + (c0 << 3);
#pragma unroll
    for (int i = 0; i < 2; ++i) {
      dv[i] = *(const float4*)(data  + base + (i << 2));
      zv[i] = *(const float4*)(noise + base + (i << 2));
      pv[i] = *(const float4*)(pmean + base + (i << 2));
      gv[i] = *(const float4*)(plogv + base + (i << 2));
    }
  };

  auto SPLIT8 = [&](const float4* v, uint4& H, uint4& M, uint4& L) {
    uint32_t h[4], m[4], lo[4];
    const float* f = (const float*)v;
#pragma unroll
    for (int p = 0; p < 4; ++p) {
      const float a = f[2 * p], b = f[2 * p + 1];
      const uint32_t ha = __float_as_uint(a) & 0xFFFF0000u;
      const uint32_t hb = __float_as_uint(b) & 0xFFFF0000u;
      h[p] = (ha >> 16) | hb;
      const float ra = a - __uint_as_float(ha);
      const float rb = b - __uint_as_float(hb);
      const uint32_t ma = __float_as_uint(ra) & 0xFFFF0000u;
      const uint32_t mb = __float_as_uint(rb) & 0xFFFF0000u;
      m[p] = (ma >> 16) | mb;
      const float sa = ra - __uint_as_float(ma);
      const float sb = rb - __uint_as_float(mb);
      lo[p] = (__float_as_uint(sa) >> 16) | (__float_as_uint(sb) & 0xFFFF0000u);
    }
    H = uint4{h[0], h[1], h[2], h[3]};
    M = uint4{m[0], m[1], m[2], m[3]};
    L = uint4{lo[0], lo[1], lo[2], lo[3]};
  };

  // split + elem + z2 on the regs from the last LOAD (register-only; the
  // compiler interleaves this VALU work with the MFMA stream below)
  auto SPLITCALC = [&]() {
    const float* df = (const float*)dv;
    const float* zf = (const float*)zv;
    const float* pf = (const float*)pv;
    const float* gf = (const float*)gv;
#pragma unroll
    for (int p = 0; p < 8; ++p) {
      const float d = df[p], z = zf[p], pm = pf[p], pl = gf[p];
      const float fc = d - z;
      eacc += 0.5f * (pm * pm + __expf(pl) * pl) - pm * fc;
      z2acc += z * z;
    }
    SPLIT8(zv, sZ[0], sZ[1], sZ[2]);
    SPLIT8(dv, sD[0], sD[1], sD[2]);
  };

  auto DSW = [&]() {
    char* base = (char*)lds + sr * 128 + ((c0 ^ (sr & 7)) << 4);
#pragma unroll
    for (int sp = 0; sp < 3; ++sp) {
      *(uint4*)(base + sp * 8192)       = sZ[sp];
      *(uint4*)(base + (3 + sp) * 8192) = sD[sp];
    }
  };

  auto MMA = [&]() {
#pragma unroll
    for (int s2 = 0; s2 < 2; ++s2) {
      const int rA   = m0 + (l & 15);
      const int cA   = (s2 << 2) + (l >> 4);
      const int offA = rA * 128 + ((cA ^ (rA & 7)) << 4);
      bf16x8 af[3];
#pragma unroll
      for (int sp = 0; sp < 3; ++sp)
        af[sp] = *(const bf16x8*)((const char*)lds + (g * 3 + sp) * 8192 + offA);
#pragma unroll
      for (int b = 0; b < 4; ++b) {
        const int rB   = (b << 4) + (l & 15);
        const int offB = rB * 128 + ((cA ^ (rB & 7)) << 4);
        bf16x8 bd[3];
#pragma unroll
        for (int sp = 0; sp < 3; ++sp)
          bd[sp] = *(const bf16x8*)((const char*)lds + (3 + sp) * 8192 + offB);
        acc[b] = MFMA(af[0], bd[0], acc[b]);
        acc[b] = MFMA(af[0], bd[1], acc[b]);
        acc[b] = MFMA(af[1], bd[0], acc[b]);
        acc[b] = MFMA(af[1], bd[1], acc[b]);
        acc[b] = MFMA(af[0], bd[2], acc[b]);
        acc[b] = MFMA(af[2], bd[0], acc[b]);
      }
    }
  };

  // prologue: stage tile 0, issue loads for tile 1
  LOAD(0);
  SPLITCALC();
  DSW();
  LOAD(1);
  __syncthreads();                     // tile 0 visible

  for (int s = 0; s < SUBT; ++s) {
    if (s + 1 < SUBT) SPLITCALC();     // VALU stream (tile s+1)
    MMA();                             // MFMA stream (tile s) — co-issued
    __syncthreads();                   // tile s reads done
    if (s + 1 < SUBT) {
      DSW();                           // commit tile s+1
      if (s + 2 < SUBT) LOAD(s + 2);   // issue next loads
      __syncthreads();                 // tile s+1 visible
    }
  }

  // ---- z2 (8 staging lanes per row) / elem reductions ----
  {
    float v = z2acc;
    v += __shfl_xor(v, 1);
    v += __shfl_xor(v, 2);
    v += __shfl_xor(v, 4);
    if ((l & 7) == 0) {
      if (ATOMIC) atomicAdd(ws + WS_Z2 + sr, v);
      else        dst[WS_Z2 + sr] = v;
    }
  }
  {
    float ev = eacc;
#pragma unroll
    for (int m = 1; m <= 32; m <<= 1) ev += __shfl_xor(ev, m);
    if (l == 0) esm[wv] = ev;
  }
  __syncthreads();
  if (t == 0) {
    float s0 = 0.f;
#pragma unroll
    for (int e = 0; e < 8; ++e) s0 += esm[e];
    if (ATOMIC) atomicAdd(ws + WS_ELEM, s0);
    else        dst[WS_ELEM] = s0;
  }

  // ---- gram stores: C/D layout col=lane&15, row=4*(lane>>4)+reg ----
  const int grOff = (g == 0) ? WS_ZD : WS_DD;
#pragma unroll
  for (int b = 0; b < 4; ++b)
#pragma unroll
    for (int rg = 0; rg < 4; ++rg) {
      const int row = m0 + ((l >> 4) << 2) + rg;
      const int col = (b << 4) + (l & 15);
      if (ATOMIC) atomicAdd(ws + grOff + row * 64 + col, acc[b][rg]);
      else        dst[grOff + row * 64 + col] = acc[b][rg];
    }
}

// Fold NB per-block partials into ws[0..NRED). 8-way atomic contention only.
// (R7 version: 1040 shallow blocks -- the 130-block deep-gather variant of
// R9-R11 was latency-bound, ~+10us.)
__global__ void k_reduce(const float* __restrict__ bigp, float* __restrict__ ws,
                         int nb) {
  const int idx = blockIdx.x * 64 + threadIdx.x;
  if (idx >= NRED) return;
  const int per = nb >> 3;
  const size_t b0 = (size_t)blockIdx.y * per;
  float s = 0.f;
#pragma unroll 4
  for (int b = 0; b < per; ++b)
    s += bigp[(b0 + b) * PSTRIDE + idx];
  atomicAdd(ws + idx, s);
}

// ---------------------------------------------------------------------------
// k_small: per row i — reconstruct cross/d2/n2 from Grams, softmax, then
//   sum_k u^2 = (w^T DD w - 2 w.cross_i + n2_i) / (1 - t + eps)^2
//   cross_ij = (1-t) ZD[i][j] + t DD[i][j]
//   n2_i = (1-t)^2 z2_i + 2t(1-t) ZD[i][i] + t^2 DD[i][i]
// ---------------------------------------------------------------------------
__global__ void k_small(const float* __restrict__ times, float* __restrict__ ws) {
  const int i = blockIdx.x;
  const int j = threadIdx.x;
  const double tt = (double)(times[i] * T_SCALE);
  const double omt = 1.0 - tt;
  const double var = omt * omt + 1e-8;
  const double inv2v = 1.0 / (2.0 * var);
  const double zd = (double)ws[WS_ZD + (i << 6) + j];
  const double dd = (double)ws[WS_DD + (i << 6) + j];
  const double cross = omt * zd + tt * dd;
  const double d2j = (double)ws[WS_DD + j * 65];
  const double lg = (2.0 * tt * cross - tt * tt * d2j) * inv2v;
  double m = lg;
#pragma unroll
  for (int msk = 1; msk <= 32; msk <<= 1) m = fmax(m, __shfl_xor(m, msk));
  const double e = exp(lg - m);
  double S = e;
#pragma unroll
  for (int msk = 1; msk <= 32; msk <<= 1) S += __shfl_xor(S, msk);
  const double wgt = e / S;

  __shared__ double wsh[64];
  wsh[j] = wgt;
  __syncthreads();
  double inner = 0.0;
#pragma unroll 8
  for (int j2 = 0; j2 < 64; ++j2)
    inner += wsh[j2] * (double)ws[WS_DD + (j << 6) + j2];
  double s1 = wgt * inner;
  double s2 = wgt * cross;
#pragma unroll
  for (int msk = 1; msk <= 32; msk <<= 1) {
    s1 += __shfl_xor(s1, msk);
    s2 += __shfl_xor(s2, msk);
  }
  if (j == 0) {
    const double zdii = (double)ws[WS_ZD + i * 65];
    const double d2i  = (double)ws[WS_DD + i * 65];
    const double z2i  = (double)ws[WS_Z2 + i];
    const double n2   = omt * omt * z2i + 2.0 * tt * omt * zdii + tt * tt * d2i;
    const double den  = omt + 1e-8;
    ws[WS_U2 + i] = (float)((s1 - 2.0 * s2 + n2) / (den * den));
  }
}

__global__ void k_final(const float* __restrict__ ws, float* __restrict__ out) {
  const int t = threadIdx.x;
  double v = 0.5 * (double)ws[WS_U2 + t];
  if (t == 0) v += (double)ws[WS_ELEM];
#pragma unroll
  for (int m = 1; m <= 32; m <<= 1) v += __shfl_xor(v, m);
  if (t == 0) out[0] = (float)(v / (double)((size_t)BB * DDIM));
}

}  // namespace

extern "C" void kernel_launch(void* const* d_in, const int* in_sizes, int n_in,
                              void* d_out, int out_size, void* d_ws, size_t ws_size,
                              hipStream_t stream) {
  const float* data  = (const float*)d_in[0];
  const float* noise = (const float*)d_in[1];
  const float* times = (const float*)d_in[2];
  const float* pmean = (const float*)d_in[3];
  const float* plogv = (const float*)d_in[4];
  float* out = (float*)d_out;
  float* ws  = (float*)d_ws;
  float* bigp = ws + WS_BIGP;

  const bool fits512 =
      ws_size >= ((size_t)WS_BIGP + (size_t)512 * PSTRIDE) * sizeof(float);

  k_init<<<dim3(33), dim3(256), 0, stream>>>(ws);
  if (fits512) {
    k_main<6, false><<<dim3(512), dim3(512), 0, stream>>>(
        data, noise, pmean, plogv, ws, bigp);
    k_reduce<<<dim3(130, 8), dim3(64), 0, stream>>>(bigp, ws, 512);
  } else {
    k_main<6, true><<<dim3(512), dim3(512), 0, stream>>>(
        data, noise, pmean, plogv, ws, bigp);
  }
  k_small<<<dim3(64), dim3(64), 0, stream>>>(times, ws);
  k_final<<<dim3(1), dim3(64), 0, stream>>>(ws, out);
}